// Round 1
// baseline (324.455 us; speedup 1.0000x reference)
//
#include <hip/hip_runtime.h>
#include <math.h>

// Problem constants
#define NB   256            // N nodes
#define EDIM 16             // edge MLP hidden
#define FINN 32             // Fin
#define FOUTN 32            // Fout
#define BT   128            // B*T
#define KKD  (NB * EDIM)    // 4096  (GEMM K: j*16+e)
#define CCD  (BT * FOUTN)   // 4096  (GEMM cols: bt*32+o)

__device__ __forceinline__ float gelu_f(float v) {
    // exact gelu: 0.5*v*(1+erf(v/sqrt(2)))
    return 0.5f * v * (1.0f + erff(v * 0.70710678118654752f));
}

// ---------------------------------------------------------------------------
// Stage 1: H[i*4096 + j*16 + e] = gelu(adj[i,j]*w1[e] + b1[e])
// 65536 threads, one per (i,j); 4 float4 stores each (fully contiguous).
// ---------------------------------------------------------------------------
__global__ void h_kernel(const float* __restrict__ adj,
                         const float* __restrict__ w1,
                         const float* __restrict__ b1,
                         float* __restrict__ H) {
    int gid = blockIdx.x * blockDim.x + threadIdx.x;   // 0..65535 = i*256+j
    float a = adj[gid];
    float4* out4 = (float4*)(H + (size_t)gid * EDIM);
    #pragma unroll
    for (int q = 0; q < 4; ++q) {
        float4 v;
        v.x = gelu_f(a * w1[q*4+0] + b1[q*4+0]);
        v.y = gelu_f(a * w1[q*4+1] + b1[q*4+1]);
        v.z = gelu_f(a * w1[q*4+2] + b1[q*4+2]);
        v.w = gelu_f(a * w1[q*4+3] + b1[q*4+3]);
        out4[q] = v;
    }
}

// ---------------------------------------------------------------------------
// Stage 2: Y2[(j*16+e)*4096 + bt*32+o] = sum_f x[bt,j,f] * w2[e*1024 + f*32 + o]
// grid (128 bt, 2 j-halves) x 512 threads; thread = (e,o); w2 column in regs,
// x row broadcast from LDS.
// ---------------------------------------------------------------------------
__global__ void y_kernel(const float* __restrict__ x,
                         const float* __restrict__ w2,
                         float* __restrict__ Y2) {
    __shared__ float xs[128 * FINN];   // 16 KiB
    int bt  = blockIdx.x;
    int jh  = blockIdx.y;
    int tid = threadIdx.x;             // 0..511
    const float4* xb4 = (const float4*)(x + ((size_t)bt * NB + jh * 128) * FINN);
    float4* xs4 = (float4*)xs;
    for (int q = tid; q < 128 * FINN / 4; q += 512) xs4[q] = xb4[q];
    __syncthreads();

    int e = tid >> 5;                  // 0..15
    int o = tid & 31;                  // 0..31
    float wc[FINN];
    #pragma unroll
    for (int f = 0; f < FINN; ++f) wc[f] = w2[e * (FINN * FOUTN) + f * FOUTN + o];

    int jbase = jh * 128;
    for (int j = 0; j < 128; ++j) {
        const float* xr = xs + j * FINN;
        float acc = 0.f;
        #pragma unroll
        for (int f = 0; f < FINN; ++f) acc += xr[f] * wc[f];
        Y2[((size_t)(jbase + j) * EDIM + e) * CCD + (size_t)bt * FOUTN + o] = acc;
    }
}

// ---------------------------------------------------------------------------
// Stage 3: AGG(256 x 4096) = H(256 x 4096) @ Y2(4096 x 4096), fp32 tiled.
// 64x64 block tile, 256 threads, 4x4 per thread, K-tile 16.
// ---------------------------------------------------------------------------
#define TM 64
#define TN 64
#define TKK 16
#define LDA 68   // pad: 68*4B = 272B, multiple of 16B -> float4-aligned rows

__global__ void gemm_kernel(const float* __restrict__ H,
                            const float* __restrict__ Y2,
                            float* __restrict__ AGG) {
    __shared__ float As[TKK][LDA];   // transposed: As[kk][m]
    __shared__ float Bs[TKK][LDA];   // Bs[kk][n]
    int tid = threadIdx.x;
    int i0 = blockIdx.y * TM;
    int c0 = blockIdx.x * TN;
    int tx = tid & 15, ty = tid >> 4;

    int am = tid >> 2;             // 0..63 (m for A staging)
    int aq = (tid & 3) * 4;        // 0,4,8,12 (k offset for A staging)
    int bk = tid >> 4;             // 0..15 (k for B staging)
    int bn = (tid & 15) * 4;       // 0..60 (n for B staging)

    float acc[4][4] = {};

    for (int k0 = 0; k0 < KKD; k0 += TKK) {
        __syncthreads();
        float4 a4 = *(const float4*)(H + (size_t)(i0 + am) * KKD + k0 + aq);
        As[aq + 0][am] = a4.x; As[aq + 1][am] = a4.y;
        As[aq + 2][am] = a4.z; As[aq + 3][am] = a4.w;
        float4 b4 = *(const float4*)(Y2 + (size_t)(k0 + bk) * CCD + c0 + bn);
        *(float4*)&Bs[bk][bn] = b4;
        __syncthreads();
        #pragma unroll
        for (int kk = 0; kk < TKK; ++kk) {
            float4 av = *(const float4*)&As[kk][ty * 4];
            float4 bv = *(const float4*)&Bs[kk][tx * 4];
            float amv[4] = {av.x, av.y, av.z, av.w};
            float bnv[4] = {bv.x, bv.y, bv.z, bv.w};
            #pragma unroll
            for (int mi = 0; mi < 4; ++mi)
                #pragma unroll
                for (int ni = 0; ni < 4; ++ni)
                    acc[mi][ni] += amv[mi] * bnv[ni];
        }
    }
    #pragma unroll
    for (int mi = 0; mi < 4; ++mi) {
        float4 v = {acc[mi][0], acc[mi][1], acc[mi][2], acc[mi][3]};
        *(float4*)(AGG + (size_t)(i0 + ty * 4 + mi) * CCD + c0 + tx * 4) = v;
    }
}

// ---------------------------------------------------------------------------
// Stage 4: y[bt,i,o] = gelu( x[bt,i,:]@node_w[:,o] + node_b[o]
//                            + AGG[i, bt*32+o] + sum_f S[bt,f]*b2[f,o] )
// one block per bt.
// ---------------------------------------------------------------------------
__global__ void out_kernel(const float* __restrict__ x,
                           const float* __restrict__ b2,
                           const float* __restrict__ node_w,
                           const float* __restrict__ node_b,
                           const float* __restrict__ AGG,
                           float* __restrict__ y) {
    __shared__ float xs[NB * FINN];     // 32 KiB
    __shared__ float nw[FINN * FOUTN];  // 4 KiB
    __shared__ float S[FINN];
    __shared__ float bias2[FOUTN];
    int bt = blockIdx.x;
    int tid = threadIdx.x;              // 0..255

    const float4* xb4 = (const float4*)(x + (size_t)bt * NB * FINN);
    float4* xs4 = (float4*)xs;
    for (int q = tid; q < NB * FINN / 4; q += 256) xs4[q] = xb4[q];
    ((float4*)nw)[tid] = ((const float4*)node_w)[tid];   // 256 float4 = 1024 floats
    __syncthreads();

    if (tid < FINN) {
        float s = 0.f;
        for (int j = 0; j < NB; ++j) s += xs[j * FINN + tid];
        S[tid] = s;
    }
    __syncthreads();
    if (tid < FOUTN) {
        float bb = node_b[tid];
        #pragma unroll
        for (int f = 0; f < FINN; ++f) bb += S[f] * b2[f * FOUTN + tid];
        bias2[tid] = bb;
    }
    __syncthreads();

    for (int r = 0; r < 32; ++r) {
        int idx = r * 256 + tid;
        int i = idx >> 5, o = idx & 31;
        float v = AGG[(size_t)i * CCD + (size_t)bt * FOUTN + o] + bias2[o];
        const float* xr = xs + i * FINN;
        #pragma unroll
        for (int f = 0; f < FINN; ++f) v += xr[f] * nw[f * FOUTN + o];
        y[(size_t)((size_t)bt * NB + i) * FOUTN + o] = gelu_f(v);
    }
}

// ---------------------------------------------------------------------------
extern "C" void kernel_launch(void* const* d_in, const int* in_sizes, int n_in,
                              void* d_out, int out_size, void* d_ws, size_t ws_size,
                              hipStream_t stream) {
    const float* x      = (const float*)d_in[0];
    const float* adj    = (const float*)d_in[1];
    const float* w1     = (const float*)d_in[2];
    const float* b1     = (const float*)d_in[3];
    const float* w2     = (const float*)d_in[4];
    const float* b2     = (const float*)d_in[5];
    const float* node_w = (const float*)d_in[6];
    const float* node_b = (const float*)d_in[7];
    float* out = (float*)d_out;

    float* ws  = (float*)d_ws;
    float* H   = ws;                              // 256*4096      = 1,048,576 f
    float* Y2  = H + (size_t)NB * KKD;            // 4096*4096     = 16,777,216 f
    float* AGG = Y2 + (size_t)KKD * CCD;          // 256*4096      = 1,048,576 f
    // total ws: 75,497,472 bytes

    hipLaunchKernelGGL(h_kernel, dim3(NB * NB / 256), dim3(256), 0, stream,
                       adj, w1, b1, H);
    hipLaunchKernelGGL(y_kernel, dim3(BT, 2), dim3(512), 0, stream,
                       x, w2, Y2);
    hipLaunchKernelGGL(gemm_kernel, dim3(CCD / TN, NB / TM), dim3(256), 0, stream,
                       H, Y2, AGG);
    hipLaunchKernelGGL(out_kernel, dim3(BT), dim3(256), 0, stream,
                       x, b2, node_w, node_b, AGG, out);
}

// Round 2
// 186.089 us; speedup vs baseline: 1.7435x; 1.7435x over previous
//
#include <hip/hip_runtime.h>
#include <math.h>

// Problem constants
#define NB   256            // N nodes
#define EDIM 16             // edge MLP hidden
#define FINN 32             // Fin
#define FOUTN 32            // Fout
#define BT   128            // B*T
#define KKD  4096           // GEMM K: j*16+e
#define CCD  4096           // GEMM cols: bt*32+o

typedef __attribute__((ext_vector_type(8))) short short8;   // 8 bf16 = 4 VGPRs
typedef __attribute__((ext_vector_type(4))) float floatx4;  // MFMA accumulator

__device__ __forceinline__ float gelu_f(float v) {
    return 0.5f * v * (1.0f + erff(v * 0.70710678118654752f));
}

// fp32 -> bf16 round-to-nearest-even
__device__ __forceinline__ ushort f2bf(float x) {
    union { float f; unsigned u; } v; v.f = x;
    unsigned r = (v.u + 0x7FFFu + ((v.u >> 16) & 1u)) >> 16;
    return (ushort)r;
}

// ---------------------------------------------------------------------------
// Stage 1: H[i*4096 + j*16 + e] = bf16(gelu(adj[i,j]*w1[e] + b1[e]))
// ---------------------------------------------------------------------------
__global__ void h_kernel(const float* __restrict__ adj,
                         const float* __restrict__ w1,
                         const float* __restrict__ b1,
                         ushort* __restrict__ H) {
    int gid = blockIdx.x * blockDim.x + threadIdx.x;   // i*256+j
    float a = adj[gid];
    ushort tmp[16];
    #pragma unroll
    for (int e = 0; e < 16; ++e) tmp[e] = f2bf(gelu_f(a * w1[e] + b1[e]));
    int4* dst = (int4*)(H + (size_t)gid * EDIM);
    dst[0] = *(int4*)&tmp[0];
    dst[1] = *(int4*)&tmp[8];
}

// ---------------------------------------------------------------------------
// Stage 2: Y2T[(bt*32+o)*4096 + j*16+e] = bf16( sum_f x[bt,j,f]*w2[e,f*32+o] )
// Transposed (c-major, k-contiguous) so GEMM B-fragments are ds_read_b128.
// Block = bt (128 blocks) x 512 threads; thread owns (e,o), w2 column in regs.
// j processed in chunks of 16; LDS transpose buffer keeps global stores
// fully coalesced.
// ---------------------------------------------------------------------------
__global__ __launch_bounds__(512) void y2t_kernel(const float* __restrict__ x,
                                                  const float* __restrict__ w2,
                                                  ushort* __restrict__ Y2T) {
    __shared__ float xs[16][FINN];    // 2 KiB: 16 j-rows of x
    __shared__ float buf[32][257];    // 32 KiB (+pad): [o][jl*16+e]
    int bt  = blockIdx.x;
    int tid = threadIdx.x;            // 0..511
    int e = tid >> 5;                 // 0..15
    int o = tid & 31;                 // 0..31

    float wc[FINN];
    #pragma unroll
    for (int f = 0; f < FINN; ++f) wc[f] = w2[e * (FINN * FOUTN) + f * FOUTN + o];

    const float* xb = x + (size_t)bt * NB * FINN;
    int oo  = tid >> 4;               // 0..31 (store phase)
    int seg = (tid & 15) * 16;        // 0..240

    for (int chunk = 0; chunk < NB / 16; ++chunk) {
        // load 16 rows x 32 f = 512 floats (1 per thread, contiguous)
        xs[tid >> 5][tid & 31] = xb[chunk * 512 + tid];
        __syncthreads();
        #pragma unroll
        for (int jl = 0; jl < 16; ++jl) {
            const float* xr = xs[jl];
            float acc = 0.f;
            #pragma unroll
            for (int f = 0; f < FINN; ++f) acc += xr[f] * wc[f];
            buf[o][jl * 16 + e] = acc;
        }
        __syncthreads();
        // store: thread -> (oo, 16-elem segment); contiguous bf16 rows
        ushort tmp[16];
        #pragma unroll
        for (int i = 0; i < 16; ++i) tmp[i] = f2bf(buf[oo][seg + i]);
        int4* dst = (int4*)(Y2T + (size_t)(bt * 32 + oo) * KKD + chunk * 256 + seg);
        dst[0] = *(int4*)&tmp[0];
        dst[1] = *(int4*)&tmp[8];
        __syncthreads();
    }
}

// ---------------------------------------------------------------------------
// Stage 3: AGG(256 x 4096) = H(256 x 4096) @ Y2T(4096 x 4096)^T  [bf16 MFMA]
// AGG[i][c] = sum_k H[i][k] * Y2T[c][k]
// 64x64 tile, BK=64, 256 threads = 4 waves, each wave 32x32 (2x2 MFMA tiles).
// Register-prefetch pipeline over the single LDS buffer.
// ---------------------------------------------------------------------------
#define BM 64
#define BN 64
#define BK 64
#define LDK 72   // padded LDS row (bf16): 144 B stride -> 2-way bank alias (free)

__global__ __launch_bounds__(256) void gemm_mfma(const ushort* __restrict__ H,
                                                 const ushort* __restrict__ Y2T,
                                                 float* __restrict__ AGG) {
    __shared__ ushort As[BM][LDK];   // 9 KiB
    __shared__ ushort Bs[BN][LDK];   // 9 KiB
    int tid  = threadIdx.x;
    int i0   = blockIdx.y * BM;      // M block (4)
    int c0   = blockIdx.x * BN;      // N block (64)
    int wave = tid >> 6;             // 0..3
    int lane = tid & 63;
    int wm = wave & 1, wn = wave >> 1;
    int mrow = lane & 15;            // m (A) / n (B) / col (C)
    int quad = lane >> 4;            // k-octet select / row-quad (C)

    // staging map: thread loads rows sr and sr+32, 8 bf16 (16B) each, A and B
    int sr = tid >> 3;               // 0..31
    int sk = (tid & 7) * 8;          // 0..56

    const int4* gA0 = (const int4*)(H   + (size_t)(i0 + sr)      * KKD + sk);
    const int4* gA1 = (const int4*)(H   + (size_t)(i0 + sr + 32) * KKD + sk);
    const int4* gB0 = (const int4*)(Y2T + (size_t)(c0 + sr)      * KKD + sk);
    const int4* gB1 = (const int4*)(Y2T + (size_t)(c0 + sr + 32) * KKD + sk);

    floatx4 acc[2][2] = {};

    // prefetch tile 0
    int4 ra0 = gA0[0], ra1 = gA1[0], rb0 = gB0[0], rb1 = gB1[0];

    for (int k0 = 0; k0 < KKD; k0 += BK) {
        *(int4*)&As[sr][sk]      = ra0;
        *(int4*)&As[sr + 32][sk] = ra1;
        *(int4*)&Bs[sr][sk]      = rb0;
        *(int4*)&Bs[sr + 32][sk] = rb1;
        __syncthreads();

        if (k0 + BK < KKD) {   // prefetch next tile (overlaps MFMA below)
            int off = (k0 + BK) / 8;   // int4 index along k
            ra0 = gA0[off]; ra1 = gA1[off];
            rb0 = gB0[off]; rb1 = gB1[off];
        }

        #pragma unroll
        for (int kk = 0; kk < BK; kk += 32) {
            short8 a0 = *(short8*)&As[wm * 32 +      mrow][kk + quad * 8];
            short8 a1 = *(short8*)&As[wm * 32 + 16 + mrow][kk + quad * 8];
            short8 b0 = *(short8*)&Bs[wn * 32 +      mrow][kk + quad * 8];
            short8 b1 = *(short8*)&Bs[wn * 32 + 16 + mrow][kk + quad * 8];
            acc[0][0] = __builtin_amdgcn_mfma_f32_16x16x32_bf16(a0, b0, acc[0][0], 0, 0, 0);
            acc[0][1] = __builtin_amdgcn_mfma_f32_16x16x32_bf16(a0, b1, acc[0][1], 0, 0, 0);
            acc[1][0] = __builtin_amdgcn_mfma_f32_16x16x32_bf16(a1, b0, acc[1][0], 0, 0, 0);
            acc[1][1] = __builtin_amdgcn_mfma_f32_16x16x32_bf16(a1, b1, acc[1][1], 0, 0, 0);
        }
        __syncthreads();
    }

    // epilogue: C/D layout col=lane&15, row=quad*4+reg
    #pragma unroll
    for (int tm = 0; tm < 2; ++tm)
        #pragma unroll
        for (int tn = 0; tn < 2; ++tn) {
            int col = c0 + wn * 32 + tn * 16 + mrow;
            #pragma unroll
            for (int r = 0; r < 4; ++r) {
                int row = i0 + wm * 32 + tm * 16 + quad * 4 + r;
                AGG[(size_t)row * CCD + col] = acc[tm][tn][r];
            }
        }
}

// ---------------------------------------------------------------------------
// Stage 4: y[bt,i,o] = gelu( x[bt,i,:]@node_w[:,o] + node_b[o]
//                            + AGG[i, bt*32+o] + sum_f S[bt,f]*b2[f,o] )
// ---------------------------------------------------------------------------
__global__ void out_kernel(const float* __restrict__ x,
                           const float* __restrict__ b2,
                           const float* __restrict__ node_w,
                           const float* __restrict__ node_b,
                           const float* __restrict__ AGG,
                           float* __restrict__ y) {
    __shared__ float xs[NB * FINN];     // 32 KiB
    __shared__ float nw[FINN * FOUTN];  // 4 KiB
    __shared__ float S[FINN];
    __shared__ float bias2[FOUTN];
    int bt = blockIdx.x;
    int tid = threadIdx.x;              // 0..255

    const float4* xb4 = (const float4*)(x + (size_t)bt * NB * FINN);
    float4* xs4 = (float4*)xs;
    for (int q = tid; q < NB * FINN / 4; q += 256) xs4[q] = xb4[q];
    ((float4*)nw)[tid] = ((const float4*)node_w)[tid];
    __syncthreads();

    if (tid < FINN) {
        float s = 0.f;
        for (int j = 0; j < NB; ++j) s += xs[j * FINN + tid];
        S[tid] = s;
    }
    __syncthreads();
    if (tid < FOUTN) {
        float bb = node_b[tid];
        #pragma unroll
        for (int f = 0; f < FINN; ++f) bb += S[f] * b2[f * FOUTN + tid];
        bias2[tid] = bb;
    }
    __syncthreads();

    for (int r = 0; r < 32; ++r) {
        int idx = r * 256 + tid;
        int i = idx >> 5, o = idx & 31;
        float v = AGG[(size_t)i * CCD + (size_t)bt * FOUTN + o] + bias2[o];
        const float* xr = xs + i * FINN;
        #pragma unroll
        for (int f = 0; f < FINN; ++f) v += xr[f] * nw[f * FOUTN + o];
        y[(size_t)((size_t)bt * NB + i) * FOUTN + o] = gelu_f(v);
    }
}

// ---------------------------------------------------------------------------
extern "C" void kernel_launch(void* const* d_in, const int* in_sizes, int n_in,
                              void* d_out, int out_size, void* d_ws, size_t ws_size,
                              hipStream_t stream) {
    const float* x      = (const float*)d_in[0];
    const float* adj    = (const float*)d_in[1];
    const float* w1     = (const float*)d_in[2];
    const float* b1     = (const float*)d_in[3];
    const float* w2     = (const float*)d_in[4];
    const float* b2     = (const float*)d_in[5];
    const float* node_w = (const float*)d_in[6];
    const float* node_b = (const float*)d_in[7];
    float* out = (float*)d_out;

    ushort* H   = (ushort*)d_ws;                      // 256*4096 bf16  = 2 MiB
    ushort* Y2T = H + (size_t)NB * KKD;               // 4096*4096 bf16 = 32 MiB
    float*  AGG = (float*)(Y2T + (size_t)CCD * KKD);  // 256*4096 f32   = 4 MiB

    hipLaunchKernelGGL(h_kernel, dim3(NB * NB / 256), dim3(256), 0, stream,
                       adj, w1, b1, H);
    hipLaunchKernelGGL(y2t_kernel, dim3(BT), dim3(512), 0, stream,
                       x, w2, Y2T);
    hipLaunchKernelGGL(gemm_mfma, dim3(CCD / BN, NB / BM), dim3(256), 0, stream,
                       H, Y2T, AGG);
    hipLaunchKernelGGL(out_kernel, dim3(BT), dim3(256), 0, stream,
                       x, b2, node_w, node_b, AGG, out);
}

// Round 3
// 136.661 us; speedup vs baseline: 2.3742x; 1.3617x over previous
//
#include <hip/hip_runtime.h>
#include <math.h>

// Problem constants
#define NB   256            // N nodes
#define EDIM 16             // edge MLP hidden
#define FINN 32             // Fin
#define FOUTN 32            // Fout
#define BT   128            // B*T
#define KKD  4096           // GEMM K index: e*256 + j   (layout choice)
#define CCD  4096           // GEMM cols:    bt*32 + o

typedef __attribute__((ext_vector_type(8))) short short8;   // 8 bf16 = 4 VGPRs
typedef __attribute__((ext_vector_type(4))) float floatx4;  // MFMA accumulator

__device__ __forceinline__ float gelu_f(float v) {
    return 0.5f * v * (1.0f + erff(v * 0.70710678118654752f));
}

// fp32 -> bf16 round-to-nearest-even
__device__ __forceinline__ ushort f2bf(float x) {
    union { float f; unsigned u; } v; v.f = x;
    unsigned r = (v.u + 0x7FFFu + ((v.u >> 16) & 1u)) >> 16;
    return (ushort)r;
}

// ---------------------------------------------------------------------------
// Stage 1: H[i][e*256 + j] = bf16(gelu(adj[i,j]*w1[e] + b1[e]))
// block = i (256 blocks), 256 threads = (e 16 x jseg 16); 32 B-run stores.
// ---------------------------------------------------------------------------
__global__ __launch_bounds__(256) void h_kernel(const float* __restrict__ adj,
                                                const float* __restrict__ w1,
                                                const float* __restrict__ b1,
                                                ushort* __restrict__ H) {
    int i   = blockIdx.x;
    int tid = threadIdx.x;
    int e   = tid >> 4;
    int seg = tid & 15;
    float w = w1[e], b = b1[e];
    const float4* arow = (const float4*)(adj + (size_t)i * NB + seg * 16);
    ushort tmp[16];
    #pragma unroll
    for (int q = 0; q < 4; ++q) {
        float4 a = arow[q];
        tmp[q*4+0] = f2bf(gelu_f(a.x * w + b));
        tmp[q*4+1] = f2bf(gelu_f(a.y * w + b));
        tmp[q*4+2] = f2bf(gelu_f(a.z * w + b));
        tmp[q*4+3] = f2bf(gelu_f(a.w * w + b));
    }
    int4* dst = (int4*)(H + (size_t)i * KKD + e * 256 + seg * 16);
    dst[0] = *(int4*)&tmp[0];
    dst[1] = *(int4*)&tmp[8];
}

// ---------------------------------------------------------------------------
// Stage 2 (MFMA, no LDS): Y2T[bt*32+o][e*256+j] = bf16(sum_f x[bt,j,f]*w2[e,f,o])
// Per 16x16x32 MFMA: D[j][o] = sum_f A[j][f] * B[f][o]
//   A-frag: x[bt][j0+ (lane&15)][quad*8 + i]  (f-contiguous float4 loads)
//   B-frag: w2[e][(quad*8+i)*32 + ot*16 + (lane&15)]  (scalar, L2-hot 64 KB)
//   D: col(lane&15)=o, row(quad*4+r)=j -> lane's 4 regs = 4 consecutive j
//      = one 8 B contiguous store into the Y2T row. No transpose needed.
// grid (4 j-quarters, 128 bt) = 512 blocks; wave w handles e in [4w,4w+4).
// ---------------------------------------------------------------------------
__global__ __launch_bounds__(256) void y2t_kernel(const float* __restrict__ x,
                                                  const float* __restrict__ w2,
                                                  ushort* __restrict__ Y2T) {
    int bt   = blockIdx.y;           // 0..127
    int jq   = blockIdx.x;           // 0..3  -> j base jq*64
    int tid  = threadIdx.x;
    int wave = tid >> 6;             // 0..3  -> e base wave*4
    int lane = tid & 63;
    int m    = lane & 15;
    int quad = lane >> 4;

    // A-frags: 4 j-tiles of 16, loaded once, reused for all 4 e's
    short8 afr[4];
    const float* xb = x + ((size_t)bt * NB + jq * 64) * FINN;
    #pragma unroll
    for (int jt = 0; jt < 4; ++jt) {
        const float* rowp = xb + (jt * 16 + m) * FINN + quad * 8;
        float4 f0 = *(const float4*)(rowp);
        float4 f1 = *(const float4*)(rowp + 4);
        short8 a;
        a[0] = (short)f2bf(f0.x); a[1] = (short)f2bf(f0.y);
        a[2] = (short)f2bf(f0.z); a[3] = (short)f2bf(f0.w);
        a[4] = (short)f2bf(f1.x); a[5] = (short)f2bf(f1.y);
        a[6] = (short)f2bf(f1.z); a[7] = (short)f2bf(f1.w);
        afr[jt] = a;
    }

    for (int ee = 0; ee < 4; ++ee) {
        int e = wave * 4 + ee;
        // B-frags for the two o-tiles
        short8 bfr[2];
        #pragma unroll
        for (int ot = 0; ot < 2; ++ot) {
            const float* wp = w2 + (size_t)e * (FINN * FOUTN)
                              + (quad * 8) * FOUTN + ot * 16 + m;
            short8 bb;
            #pragma unroll
            for (int i = 0; i < 8; ++i) bb[i] = (short)f2bf(wp[i * FOUTN]);
            bfr[ot] = bb;
        }
        #pragma unroll
        for (int jt = 0; jt < 4; ++jt) {
            #pragma unroll
            for (int ot = 0; ot < 2; ++ot) {
                floatx4 z = {0.f, 0.f, 0.f, 0.f};
                floatx4 d = __builtin_amdgcn_mfma_f32_16x16x32_bf16(
                                afr[jt], bfr[ot], z, 0, 0, 0);
                unsigned lo = (unsigned)f2bf(d[0]) | ((unsigned)f2bf(d[1]) << 16);
                unsigned hi = (unsigned)f2bf(d[2]) | ((unsigned)f2bf(d[3]) << 16);
                uint2 v; v.x = lo; v.y = hi;
                int row = bt * 32 + ot * 16 + m;
                int col = e * 256 + jq * 64 + jt * 16 + quad * 4;
                *(uint2*)(Y2T + (size_t)row * KKD + col) = v;
            }
        }
    }
}

// ---------------------------------------------------------------------------
// Stage 3: AGG(256 x 4096) = H(256 x 4096) @ Y2T(4096 x 4096)^T  [bf16 MFMA]
// (unchanged from round 2 — layout-agnostic in k)
// ---------------------------------------------------------------------------
#define BM 64
#define BN 64
#define BK 64
#define LDK 72   // padded LDS row (bf16): 144 B stride -> 2-way bank alias (free)

__global__ __launch_bounds__(256) void gemm_mfma(const ushort* __restrict__ H,
                                                 const ushort* __restrict__ Y2T,
                                                 float* __restrict__ AGG) {
    __shared__ ushort As[BM][LDK];
    __shared__ ushort Bs[BN][LDK];
    int tid  = threadIdx.x;
    int i0   = blockIdx.y * BM;
    int c0   = blockIdx.x * BN;
    int wave = tid >> 6;
    int lane = tid & 63;
    int wm = wave & 1, wn = wave >> 1;
    int mrow = lane & 15;
    int quad = lane >> 4;

    int sr = tid >> 3;
    int sk = (tid & 7) * 8;

    const int4* gA0 = (const int4*)(H   + (size_t)(i0 + sr)      * KKD + sk);
    const int4* gA1 = (const int4*)(H   + (size_t)(i0 + sr + 32) * KKD + sk);
    const int4* gB0 = (const int4*)(Y2T + (size_t)(c0 + sr)      * KKD + sk);
    const int4* gB1 = (const int4*)(Y2T + (size_t)(c0 + sr + 32) * KKD + sk);

    floatx4 acc[2][2] = {};

    int4 ra0 = gA0[0], ra1 = gA1[0], rb0 = gB0[0], rb1 = gB1[0];

    for (int k0 = 0; k0 < KKD; k0 += BK) {
        *(int4*)&As[sr][sk]      = ra0;
        *(int4*)&As[sr + 32][sk] = ra1;
        *(int4*)&Bs[sr][sk]      = rb0;
        *(int4*)&Bs[sr + 32][sk] = rb1;
        __syncthreads();

        if (k0 + BK < KKD) {
            int off = (k0 + BK) / 8;
            ra0 = gA0[off]; ra1 = gA1[off];
            rb0 = gB0[off]; rb1 = gB1[off];
        }

        #pragma unroll
        for (int kk = 0; kk < BK; kk += 32) {
            short8 a0 = *(short8*)&As[wm * 32 +      mrow][kk + quad * 8];
            short8 a1 = *(short8*)&As[wm * 32 + 16 + mrow][kk + quad * 8];
            short8 b0 = *(short8*)&Bs[wn * 32 +      mrow][kk + quad * 8];
            short8 b1 = *(short8*)&Bs[wn * 32 + 16 + mrow][kk + quad * 8];
            acc[0][0] = __builtin_amdgcn_mfma_f32_16x16x32_bf16(a0, b0, acc[0][0], 0, 0, 0);
            acc[0][1] = __builtin_amdgcn_mfma_f32_16x16x32_bf16(a0, b1, acc[0][1], 0, 0, 0);
            acc[1][0] = __builtin_amdgcn_mfma_f32_16x16x32_bf16(a1, b0, acc[1][0], 0, 0, 0);
            acc[1][1] = __builtin_amdgcn_mfma_f32_16x16x32_bf16(a1, b1, acc[1][1], 0, 0, 0);
        }
        __syncthreads();
    }

    #pragma unroll
    for (int tm = 0; tm < 2; ++tm)
        #pragma unroll
        for (int tn = 0; tn < 2; ++tn) {
            int col = c0 + wn * 32 + tn * 16 + mrow;
            #pragma unroll
            for (int r = 0; r < 4; ++r) {
                int row = i0 + wm * 32 + tm * 16 + quad * 4 + r;
                AGG[(size_t)row * CCD + col] = acc[tm][tn][r];
            }
        }
}

// ---------------------------------------------------------------------------
// Stage 4: y[bt,i,o] = gelu( x[bt,i,:]@node_w[:,o] + node_b[o]
//                            + AGG[i, bt*32+o] + sum_f S[bt,f]*b2[f,o] )
// (unchanged from round 2)
// ---------------------------------------------------------------------------
__global__ void out_kernel(const float* __restrict__ x,
                           const float* __restrict__ b2,
                           const float* __restrict__ node_w,
                           const float* __restrict__ node_b,
                           const float* __restrict__ AGG,
                           float* __restrict__ y) {
    __shared__ float xs[NB * FINN];
    __shared__ float nw[FINN * FOUTN];
    __shared__ float S[FINN];
    __shared__ float bias2[FOUTN];
    int bt = blockIdx.x;
    int tid = threadIdx.x;

    const float4* xb4 = (const float4*)(x + (size_t)bt * NB * FINN);
    float4* xs4 = (float4*)xs;
    for (int q = tid; q < NB * FINN / 4; q += 256) xs4[q] = xb4[q];
    ((float4*)nw)[tid] = ((const float4*)node_w)[tid];
    __syncthreads();

    if (tid < FINN) {
        float s = 0.f;
        for (int j = 0; j < NB; ++j) s += xs[j * FINN + tid];
        S[tid] = s;
    }
    __syncthreads();
    if (tid < FOUTN) {
        float bb = node_b[tid];
        #pragma unroll
        for (int f = 0; f < FINN; ++f) bb += S[f] * b2[f * FOUTN + tid];
        bias2[tid] = bb;
    }
    __syncthreads();

    for (int r = 0; r < 32; ++r) {
        int idx = r * 256 + tid;
        int i = idx >> 5, o = idx & 31;
        float v = AGG[(size_t)i * CCD + (size_t)bt * FOUTN + o] + bias2[o];
        const float* xr = xs + i * FINN;
        #pragma unroll
        for (int f = 0; f < FINN; ++f) v += xr[f] * nw[f * FOUTN + o];
        y[(size_t)((size_t)bt * NB + i) * FOUTN + o] = gelu_f(v);
    }
}

// ---------------------------------------------------------------------------
extern "C" void kernel_launch(void* const* d_in, const int* in_sizes, int n_in,
                              void* d_out, int out_size, void* d_ws, size_t ws_size,
                              hipStream_t stream) {
    const float* x      = (const float*)d_in[0];
    const float* adj    = (const float*)d_in[1];
    const float* w1     = (const float*)d_in[2];
    const float* b1     = (const float*)d_in[3];
    const float* w2     = (const float*)d_in[4];
    const float* b2     = (const float*)d_in[5];
    const float* node_w = (const float*)d_in[6];
    const float* node_b = (const float*)d_in[7];
    float* out = (float*)d_out;

    ushort* H   = (ushort*)d_ws;                      // 256*4096 bf16  = 2 MiB
    ushort* Y2T = H + (size_t)NB * KKD;               // 4096*4096 bf16 = 32 MiB
    float*  AGG = (float*)(Y2T + (size_t)CCD * KKD);  // 256*4096 f32   = 4 MiB

    hipLaunchKernelGGL(h_kernel, dim3(NB), dim3(256), 0, stream,
                       adj, w1, b1, H);
    hipLaunchKernelGGL(y2t_kernel, dim3(4, BT), dim3(256), 0, stream,
                       x, w2, Y2T);
    hipLaunchKernelGGL(gemm_mfma, dim3(CCD / BN, NB / BM), dim3(256), 0, stream,
                       H, Y2T, AGG);
    hipLaunchKernelGGL(out_kernel, dim3(BT), dim3(256), 0, stream,
                       x, b2, node_w, node_b, AGG, out);
}

// Round 4
// 128.451 us; speedup vs baseline: 2.5259x; 1.0639x over previous
//
#include <hip/hip_runtime.h>
#include <math.h>

// Problem constants
#define NB   256            // N nodes
#define EDIM 16             // edge MLP hidden
#define FINN 32             // Fin
#define FOUTN 32            // Fout
#define BT   128            // B*T
#define KKD  4096           // GEMM K index: e*256 + j
#define CCD  4096           // GEMM cols:    bt*32 + o

typedef __attribute__((ext_vector_type(8))) short short8;   // 8 bf16 = 4 VGPRs
typedef __attribute__((ext_vector_type(4))) float floatx4;  // MFMA accumulator

__device__ __forceinline__ float gelu_f(float v) {
    return 0.5f * v * (1.0f + erff(v * 0.70710678118654752f));
}

// fp32 -> bf16 round-to-nearest-even
__device__ __forceinline__ ushort f2bf(float x) {
    union { float f; unsigned u; } v; v.f = x;
    unsigned r = (v.u + 0x7FFFu + ((v.u >> 16) & 1u)) >> 16;
    return (ushort)r;
}

// ---------------------------------------------------------------------------
// Prep (fused): 896 blocks x 256 threads, branch on blockIdx (wave-uniform).
//   blocks [0,256):    H[i][e*256+j] = bf16(gelu(adj[i,j]*w1[e]+b1[e]))
//   blocks [256,768):  Y2T[bt*32+o][e*256+j] = bf16(sum_f x[bt,j,f]*w2[e,f,o])
//                      via LDS-free MFMA (D-layout gives contiguous j-runs)
//   blocks [768,896):  XNW2[bt*8192 + i*32 + o] = x[bt,i,:]@node_w[:,o]
//                      + node_b[o] + sum_f S[bt,f]*b2[f,o]   (out-layout, f32)
// ---------------------------------------------------------------------------
__global__ __launch_bounds__(256) void prep_kernel(
        const float* __restrict__ adj, const float* __restrict__ w1,
        const float* __restrict__ b1,  const float* __restrict__ x,
        const float* __restrict__ w2,  const float* __restrict__ b2,
        const float* __restrict__ node_w, const float* __restrict__ node_b,
        ushort* __restrict__ H, ushort* __restrict__ Y2T,
        float* __restrict__ XNW2) {
    __shared__ float xs[NB * FINN];     // 32 KiB (xnw section only)
    __shared__ float nw[FINN * FOUTN];  // 4 KiB
    __shared__ float S[FINN];
    __shared__ float bias2[FOUTN];

    int bid = blockIdx.x;
    int tid = threadIdx.x;

    if (bid < 256) {
        // ---- H section ----
        int i   = bid;
        int e   = tid >> 4;
        int seg = tid & 15;
        float w = w1[e], b = b1[e];
        const float4* arow = (const float4*)(adj + (size_t)i * NB + seg * 16);
        ushort tmp[16];
        #pragma unroll
        for (int q = 0; q < 4; ++q) {
            float4 a = arow[q];
            tmp[q*4+0] = f2bf(gelu_f(a.x * w + b));
            tmp[q*4+1] = f2bf(gelu_f(a.y * w + b));
            tmp[q*4+2] = f2bf(gelu_f(a.z * w + b));
            tmp[q*4+3] = f2bf(gelu_f(a.w * w + b));
        }
        int4* dst = (int4*)(H + (size_t)i * KKD + e * 256 + seg * 16);
        dst[0] = *(int4*)&tmp[0];
        dst[1] = *(int4*)&tmp[8];
    } else if (bid < 768) {
        // ---- Y2T section (MFMA, no LDS) ----
        int id   = bid - 256;
        int bt   = id >> 2;            // 0..127
        int jq   = id & 3;             // j base jq*64
        int wave = tid >> 6;           // e base wave*4
        int lane = tid & 63;
        int m    = lane & 15;
        int quad = lane >> 4;

        short8 afr[4];
        const float* xb = x + ((size_t)bt * NB + jq * 64) * FINN;
        #pragma unroll
        for (int jt = 0; jt < 4; ++jt) {
            const float* rowp = xb + (jt * 16 + m) * FINN + quad * 8;
            float4 f0 = *(const float4*)(rowp);
            float4 f1 = *(const float4*)(rowp + 4);
            short8 a;
            a[0] = (short)f2bf(f0.x); a[1] = (short)f2bf(f0.y);
            a[2] = (short)f2bf(f0.z); a[3] = (short)f2bf(f0.w);
            a[4] = (short)f2bf(f1.x); a[5] = (short)f2bf(f1.y);
            a[6] = (short)f2bf(f1.z); a[7] = (short)f2bf(f1.w);
            afr[jt] = a;
        }

        for (int ee = 0; ee < 4; ++ee) {
            int e = wave * 4 + ee;
            short8 bfr[2];
            #pragma unroll
            for (int ot = 0; ot < 2; ++ot) {
                const float* wp = w2 + (size_t)e * (FINN * FOUTN)
                                  + (quad * 8) * FOUTN + ot * 16 + m;
                short8 bb;
                #pragma unroll
                for (int i = 0; i < 8; ++i) bb[i] = (short)f2bf(wp[i * FOUTN]);
                bfr[ot] = bb;
            }
            #pragma unroll
            for (int jt = 0; jt < 4; ++jt) {
                #pragma unroll
                for (int ot = 0; ot < 2; ++ot) {
                    floatx4 z = {0.f, 0.f, 0.f, 0.f};
                    floatx4 d = __builtin_amdgcn_mfma_f32_16x16x32_bf16(
                                    afr[jt], bfr[ot], z, 0, 0, 0);
                    unsigned lo = (unsigned)f2bf(d[0]) | ((unsigned)f2bf(d[1]) << 16);
                    unsigned hi = (unsigned)f2bf(d[2]) | ((unsigned)f2bf(d[3]) << 16);
                    uint2 v; v.x = lo; v.y = hi;
                    int row = bt * 32 + ot * 16 + m;
                    int col = e * 256 + jq * 64 + jt * 16 + quad * 4;
                    *(uint2*)(Y2T + (size_t)row * KKD + col) = v;
                }
            }
        }
    } else {
        // ---- XNW2 section ----
        int bt = bid - 768;
        const float4* xb4 = (const float4*)(x + (size_t)bt * NB * FINN);
        float4* xs4 = (float4*)xs;
        for (int q = tid; q < NB * FINN / 4; q += 256) xs4[q] = xb4[q];
        ((float4*)nw)[tid] = ((const float4*)node_w)[tid];
        __syncthreads();

        if (tid < FINN) {
            float s = 0.f;
            for (int j = 0; j < NB; ++j) s += xs[j * FINN + tid];
            S[tid] = s;
        }
        __syncthreads();
        if (tid < FOUTN) {
            float bb = node_b[tid];
            #pragma unroll
            for (int f = 0; f < FINN; ++f) bb += S[f] * b2[f * FOUTN + tid];
            bias2[tid] = bb;
        }
        __syncthreads();

        for (int r = 0; r < 32; ++r) {
            int idx = r * 256 + tid;
            int i = idx >> 5, o = idx & 31;
            float v = bias2[o];
            const float* xr = xs + i * FINN;
            #pragma unroll
            for (int f = 0; f < FINN; ++f) v += xr[f] * nw[f * FOUTN + o];
            XNW2[(size_t)bt * (NB * FOUTN) + idx] = v;
        }
    }
}

// ---------------------------------------------------------------------------
// GEMM + epilogue: out[bt,i,o] = gelu( AGG[i][bt*32+o] + XNW2[bt,i,o] )
// AGG[i][c] = sum_k H[i][k] * Y2T[c][k]   (bf16 MFMA, fp32 accumulate)
// BM=64, BN=32 (one bt per block), BK=64; 128 threads = 2 waves, each a
// 32x32 tile (2x2 of 16x16x32). Grid (128 bt, 4 i-blocks) = 512 blocks
// -> 2 blocks/CU so barrier drains overlap across blocks.
// Epilogue: acc -> LDS C-tile -> coalesced float4 gelu store to d_out.
// ---------------------------------------------------------------------------
#define BM 64
#define BN 32
#define BK 64
#define LDK 72   // padded LDS row (bf16): 144 B stride -> 2-way alias (free)

__global__ __launch_bounds__(128) void gemm_out(const ushort* __restrict__ H,
                                                const ushort* __restrict__ Y2T,
                                                const float* __restrict__ XNW2,
                                                float* __restrict__ out) {
    __shared__ ushort As[BM][LDK];   // 9.2 KiB
    __shared__ ushort Bs[BN][LDK];   // 4.6 KiB
    __shared__ float  Cs[BM][36];    // 9.2 KiB (pad 36: +4-bank row skew)

    int tid  = threadIdx.x;          // 0..127
    int bt   = blockIdx.x;           // 0..127 -> c0 = bt*32
    int i0   = blockIdx.y * BM;      // 0..192
    int w    = tid >> 6;             // 0..1 -> rows w*32
    int lane = tid & 63;
    int mrow = lane & 15;
    int quad = lane >> 4;
    int c0   = bt * BN;

    // staging: thread covers A rows sr+{0,16,32,48}, B rows sr+{0,16}; 16 B each
    int sr = tid >> 3;               // 0..15
    int sk = (tid & 7) * 8;          // 0..56

    const int4* gA0 = (const int4*)(H   + (size_t)(i0 + sr)      * KKD + sk);
    const int4* gA1 = (const int4*)(H   + (size_t)(i0 + sr + 16) * KKD + sk);
    const int4* gA2 = (const int4*)(H   + (size_t)(i0 + sr + 32) * KKD + sk);
    const int4* gA3 = (const int4*)(H   + (size_t)(i0 + sr + 48) * KKD + sk);
    const int4* gB0 = (const int4*)(Y2T + (size_t)(c0 + sr)      * KKD + sk);
    const int4* gB1 = (const int4*)(Y2T + (size_t)(c0 + sr + 16) * KKD + sk);

    floatx4 acc[2][2] = {};

    int4 ra0 = gA0[0], ra1 = gA1[0], ra2 = gA2[0], ra3 = gA3[0];
    int4 rb0 = gB0[0], rb1 = gB1[0];

    for (int k0 = 0; k0 < KKD; k0 += BK) {
        *(int4*)&As[sr     ][sk] = ra0;
        *(int4*)&As[sr + 16][sk] = ra1;
        *(int4*)&As[sr + 32][sk] = ra2;
        *(int4*)&As[sr + 48][sk] = ra3;
        *(int4*)&Bs[sr     ][sk] = rb0;
        *(int4*)&Bs[sr + 16][sk] = rb1;
        __syncthreads();

        if (k0 + BK < KKD) {   // prefetch next tile (overlaps MFMA below)
            int off = (k0 + BK) / 8;
            ra0 = gA0[off]; ra1 = gA1[off]; ra2 = gA2[off]; ra3 = gA3[off];
            rb0 = gB0[off]; rb1 = gB1[off];
        }

        #pragma unroll
        for (int kk = 0; kk < BK; kk += 32) {
            short8 a0 = *(short8*)&As[w * 32 +      mrow][kk + quad * 8];
            short8 a1 = *(short8*)&As[w * 32 + 16 + mrow][kk + quad * 8];
            short8 b0 = *(short8*)&Bs[          mrow][kk + quad * 8];
            short8 b1 = *(short8*)&Bs[     16 + mrow][kk + quad * 8];
            acc[0][0] = __builtin_amdgcn_mfma_f32_16x16x32_bf16(a0, b0, acc[0][0], 0, 0, 0);
            acc[0][1] = __builtin_amdgcn_mfma_f32_16x16x32_bf16(a0, b1, acc[0][1], 0, 0, 0);
            acc[1][0] = __builtin_amdgcn_mfma_f32_16x16x32_bf16(a1, b0, acc[1][0], 0, 0, 0);
            acc[1][1] = __builtin_amdgcn_mfma_f32_16x16x32_bf16(a1, b1, acc[1][1], 0, 0, 0);
        }
        __syncthreads();
    }

    // C/D layout: col = tn*16 + mrow, row = w*32 + tm*16 + quad*4 + r
    #pragma unroll
    for (int tm = 0; tm < 2; ++tm)
        #pragma unroll
        for (int tn = 0; tn < 2; ++tn)
            #pragma unroll
            for (int r = 0; r < 4; ++r)
                Cs[w * 32 + tm * 16 + quad * 4 + r][tn * 16 + mrow] = acc[tm][tn][r];
    __syncthreads();

    // out slice for this block: out[(bt*256 + i0)*32 .. +2048)  (contiguous)
    size_t base = ((size_t)bt * NB + i0) * FOUTN;
    const float4* xn4 = (const float4*)(XNW2 + base);
    float4*       ot4 = (float4*)(out + base);
    #pragma unroll
    for (int q = 0; q < 4; ++q) {
        int idx = tid * 16 + q * 4;        // 0..2044, aligned to 4
        int il = idx >> 5, o = idx & 31;
        float4 xv = xn4[idx >> 2];
        float4 v;
        v.x = gelu_f(Cs[il][o + 0] + xv.x);
        v.y = gelu_f(Cs[il][o + 1] + xv.y);
        v.z = gelu_f(Cs[il][o + 2] + xv.z);
        v.w = gelu_f(Cs[il][o + 3] + xv.w);
        ot4[idx >> 2] = v;
    }
}

// ---------------------------------------------------------------------------
extern "C" void kernel_launch(void* const* d_in, const int* in_sizes, int n_in,
                              void* d_out, int out_size, void* d_ws, size_t ws_size,
                              hipStream_t stream) {
    const float* x      = (const float*)d_in[0];
    const float* adj    = (const float*)d_in[1];
    const float* w1     = (const float*)d_in[2];
    const float* b1     = (const float*)d_in[3];
    const float* w2     = (const float*)d_in[4];
    const float* b2     = (const float*)d_in[5];
    const float* node_w = (const float*)d_in[6];
    const float* node_b = (const float*)d_in[7];
    float* out = (float*)d_out;

    ushort* H    = (ushort*)d_ws;                      // 256*4096 bf16  = 2 MiB
    ushort* Y2T  = H + (size_t)NB * KKD;               // 4096*4096 bf16 = 32 MiB
    float*  XNW2 = (float*)(Y2T + (size_t)CCD * KKD);  // 128*256*32 f32 = 4 MiB

    hipLaunchKernelGGL(prep_kernel, dim3(896), dim3(256), 0, stream,
                       adj, w1, b1, x, w2, b2, node_w, node_b, H, Y2T, XNW2);
    hipLaunchKernelGGL(gemm_out, dim3(BT, NB / BM), dim3(128), 0, stream,
                       H, Y2T, XNW2, out);
}

// Round 5
// 111.439 us; speedup vs baseline: 2.9115x; 1.1527x over previous
//
#include <hip/hip_runtime.h>
#include <math.h>

// Problem constants
#define NB    256           // N nodes
#define EDIM  16            // edge MLP hidden
#define FINN  32            // Fin
#define FOUTN 32            // Fout
#define BT    128           // B*T
#define KKD   4096          // GEMM K index: e*256 + j

typedef __attribute__((ext_vector_type(8))) short short8;   // 8 bf16 = 4 VGPRs
typedef __attribute__((ext_vector_type(4))) float floatx4;  // MFMA accumulator

#define MFMA16(a,b,c) __builtin_amdgcn_mfma_f32_16x16x32_bf16((a),(b),(c),0,0,0)

__device__ __forceinline__ float gelu_f(float v) {
    return 0.5f * v * (1.0f + erff(v * 0.70710678118654752f));
}
__device__ __forceinline__ ushort f2bf(float x) {
    union { float f; unsigned u; } v; v.f = x;
    unsigned r = (v.u + 0x7FFFu + ((v.u >> 16) & 1u)) >> 16;
    return (ushort)r;
}
__device__ __forceinline__ float bf2f(ushort b) {
    union { unsigned u; float f; } v; v.u = ((unsigned)b) << 16; return v.f;
}

// ---------------------------------------------------------------------------
// Stage 1: H[i][e*256 + j] = bf16(gelu(adj[i,j]*w1[e] + b1[e]))   (2 MiB)
// ---------------------------------------------------------------------------
__global__ __launch_bounds__(256) void h_kernel(const float* __restrict__ adj,
                                                const float* __restrict__ w1,
                                                const float* __restrict__ b1,
                                                ushort* __restrict__ H) {
    int i   = blockIdx.x;
    int tid = threadIdx.x;
    int e   = tid >> 4;
    int seg = tid & 15;
    float w = w1[e], b = b1[e];
    const float4* arow = (const float4*)(adj + (size_t)i * NB + seg * 16);
    ushort tmp[16];
    #pragma unroll
    for (int q = 0; q < 4; ++q) {
        float4 a = arow[q];
        tmp[q*4+0] = f2bf(gelu_f(a.x * w + b));
        tmp[q*4+1] = f2bf(gelu_f(a.y * w + b));
        tmp[q*4+2] = f2bf(gelu_f(a.z * w + b));
        tmp[q*4+3] = f2bf(gelu_f(a.w * w + b));
    }
    int4* dst = (int4*)(H + (size_t)i * KKD + e * 256 + seg * 16);
    dst[0] = *(int4*)&tmp[0];
    dst[1] = *(int4*)&tmp[8];
}

// ---------------------------------------------------------------------------
// Fused y2 + GEMM + epilogue. Block = (bt, ihalf); 256 threads = 4 waves.
//   Per chunk c (512 k = edges {2c, 2c+1}):
//     y2 phase: wave w computes Y2 slice for (e_rel=w&1, o-half=w>>1), all j,
//               via MFMA from LDS-resident bf16 x + register w2 fragments;
//               D-layout lands as 4-consecutive-j runs -> uint2 LDS store.
//     gemm phase: A-frags straight from global H (L2-hot), B from LDS chunk,
//               acc 2x2 of 16x16x32, K accumulated over all 8 chunks.
//   Double-buffered Bs; one barrier per chunk.
//   Epilogue: acc += x@node_w (one extra MFMA/tile) + bias2; gelu; store.
// ---------------------------------------------------------------------------
#define CH   512   // k per chunk
#define NCH  8
#define BSP  520   // Bs padded row (bf16): 1040 B, 16B-aligned
#define XBP  40    // xb/nwT padded row (bf16): 80 B, 16B-aligned, conflict-free

__global__ __launch_bounds__(256, 1) void fused_kernel(
        const float* __restrict__ x,      const float* __restrict__ w2,
        const float* __restrict__ b2,     const float* __restrict__ node_w,
        const float* __restrict__ node_b, const ushort* __restrict__ H,
        float* __restrict__ out) {
    __shared__ ushort xb[NB][XBP];      // 20 KiB  x[bt] in bf16
    __shared__ ushort Bs[2][32][BSP];   // 65 KiB  y2 chunk double buffer [o][k]
    __shared__ ushort nwT[32][XBP];     // 2.5 KiB node_w^T in bf16
    __shared__ float  Sp[8][32];
    __shared__ float  Sv[32];
    __shared__ float  bias2[32];

    int bt    = blockIdx.x;             // 0..127
    int ihalf = blockIdx.y;             // 0..1 -> i rows [ihalf*128, +128)
    int tid   = threadIdx.x;
    int wv    = tid >> 6;               // 0..3
    int lane  = tid & 63;
    int m     = lane & 15;
    int quad  = lane >> 4;

    // ---- fill xb (bf16) + nwT ----
    const float4* xg = (const float4*)(x + (size_t)bt * NB * FINN);
    #pragma unroll
    for (int it = 0; it < 8; ++it) {
        int idx4 = it * 256 + tid;      // 2048 float4s total
        float4 v = xg[idx4];
        int j = idx4 >> 3, f = (idx4 & 7) * 4;
        unsigned lo = (unsigned)f2bf(v.x) | ((unsigned)f2bf(v.y) << 16);
        unsigned hi = (unsigned)f2bf(v.z) | ((unsigned)f2bf(v.w) << 16);
        uint2 p; p.x = lo; p.y = hi;
        *(uint2*)&xb[j][f] = p;
    }
    {
        float4 v = ((const float4*)node_w)[tid];   // node_w[f][o], f=tid>>3
        int f = tid >> 3, o = (tid & 7) * 4;
        nwT[o + 0][f] = f2bf(v.x); nwT[o + 1][f] = f2bf(v.y);
        nwT[o + 2][f] = f2bf(v.z); nwT[o + 3][f] = f2bf(v.w);
    }
    __syncthreads();

    // ---- S partials (per-f column sums of x[bt]) ----
    {
        int f = tid & 31, grp = tid >> 5;
        float s = 0.f;
        for (int j = grp * 32; j < grp * 32 + 32; ++j) s += bf2f(xb[j][f]);
        Sp[grp][f] = s;
    }

    // ---- preload register fragments ----
    // x A-frags for y2 phase: A[j=m][f=quad*8+i], 16 j-tiles (all 256 j)
    short8 afr[16];
    #pragma unroll
    for (int jt = 0; jt < 16; ++jt)
        afr[jt] = *(short8*)&xb[jt * 16 + m][quad * 8];
    // w2 B-frags: this wave's (e_rel, ot) for every chunk
    int eoff = wv & 1;                  // e_rel
    int ot   = wv >> 1;                 // o-half
    short8 wfr[NCH];
    #pragma unroll
    for (int c = 0; c < NCH; ++c) {
        int e = 2 * c + eoff;
        const float* wp = w2 + (size_t)e * (FINN * FOUTN)
                          + (quad * 8) * FOUTN + ot * 16 + m;
        short8 bb;
        #pragma unroll
        for (int i = 0; i < 8; ++i) bb[i] = (short)f2bf(wp[i * FOUTN]);
        wfr[c] = bb;
    }
    __syncthreads();                    // Sp complete
    if (tid < 32) {
        float s = 0.f;
        #pragma unroll
        for (int g = 0; g < 8; ++g) s += Sp[g][tid];
        Sv[tid] = s;
    }

    floatx4 acc[2][2] = {};
    int i0g = ihalf * 128 + wv * 32;    // this wave's M rows in H / out

    // y2 chunk producer (c, buf compile-time via unroll)
    #define Y2CHUNK(c, buf)                                                   \
    {                                                                         \
        short8 wb = wfr[c];                                                   \
        _Pragma("unroll")                                                     \
        for (int jt = 0; jt < 16; ++jt) {                                     \
            floatx4 z = {0.f, 0.f, 0.f, 0.f};                                 \
            floatx4 d = MFMA16(afr[jt], wb, z);                               \
            unsigned lo = (unsigned)f2bf(d[0]) | ((unsigned)f2bf(d[1]) << 16);\
            unsigned hi = (unsigned)f2bf(d[2]) | ((unsigned)f2bf(d[3]) << 16);\
            uint2 pv; pv.x = lo; pv.y = hi;                                   \
            *(uint2*)&Bs[buf][ot * 16 + m][eoff * 256 + jt * 16 + quad * 4] = pv; \
        }                                                                     \
    }

    // prologue: produce chunk 0
    Y2CHUNK(0, 0);
    __syncthreads();
    if (tid < 32) {                     // bias2 (read only in epilogue)
        float bb = node_b[tid];
        #pragma unroll
        for (int f = 0; f < FINN; ++f) bb += Sv[f] * b2[f * FOUTN + tid];
        bias2[tid] = bb;
    }

    #pragma unroll
    for (int c = 0; c < NCH; ++c) {
        if (c < NCH - 1) {
            if (c + 1 == 1) Y2CHUNK(1, 1);
            if (c + 1 == 2) Y2CHUNK(2, 0);
            if (c + 1 == 3) Y2CHUNK(3, 1);
            if (c + 1 == 4) Y2CHUNK(4, 0);
            if (c + 1 == 5) Y2CHUNK(5, 1);
            if (c + 1 == 6) Y2CHUNK(6, 0);
            if (c + 1 == 7) Y2CHUNK(7, 1);
        }
        // gemm on chunk c from Bs[c&1]
        const int buf = c & 1;
        #pragma unroll
        for (int kk = 0; kk < CH; kk += 32) {
            int kg = c * CH + kk + quad * 8;
            short8 a0 = *(const short8*)(H + (size_t)(i0g +      m) * KKD + kg);
            short8 a1 = *(const short8*)(H + (size_t)(i0g + 16 + m) * KKD + kg);
            short8 b0 = *(short8*)&Bs[buf][     m][kk + quad * 8];
            short8 b1 = *(short8*)&Bs[buf][16 + m][kk + quad * 8];
            acc[0][0] = MFMA16(a0, b0, acc[0][0]);
            acc[0][1] = MFMA16(a0, b1, acc[0][1]);
            acc[1][0] = MFMA16(a1, b0, acc[1][0]);
            acc[1][1] = MFMA16(a1, b1, acc[1][1]);
        }
        __syncthreads();
    }

    // ---- epilogue: + x@node_w (one MFMA per tile), + bias2, gelu, store ----
    #pragma unroll
    for (int tm = 0; tm < 2; ++tm) {
        short8 xa = *(short8*)&xb[i0g + tm * 16 + m][quad * 8];
        #pragma unroll
        for (int tn = 0; tn < 2; ++tn) {
            short8 nb = *(short8*)&nwT[tn * 16 + m][quad * 8];
            acc[tm][tn] = MFMA16(xa, nb, acc[tm][tn]);
        }
    }
    #pragma unroll
    for (int tm = 0; tm < 2; ++tm)
        #pragma unroll
        for (int tn = 0; tn < 2; ++tn) {
            int o = tn * 16 + m;
            float bz = bias2[o];
            #pragma unroll
            for (int r = 0; r < 4; ++r) {
                int row = i0g + tm * 16 + quad * 4 + r;
                out[((size_t)bt * NB + row) * FOUTN + o] =
                    gelu_f(acc[tm][tn][r] + bz);
            }
        }
}

// ---------------------------------------------------------------------------
extern "C" void kernel_launch(void* const* d_in, const int* in_sizes, int n_in,
                              void* d_out, int out_size, void* d_ws, size_t ws_size,
                              hipStream_t stream) {
    const float* x      = (const float*)d_in[0];
    const float* adj    = (const float*)d_in[1];
    const float* w1     = (const float*)d_in[2];
    const float* b1     = (const float*)d_in[3];
    const float* w2     = (const float*)d_in[4];
    const float* b2     = (const float*)d_in[5];
    const float* node_w = (const float*)d_in[6];
    const float* node_b = (const float*)d_in[7];
    float* out = (float*)d_out;

    ushort* H = (ushort*)d_ws;          // 256*4096 bf16 = 2 MiB (only ws use)

    hipLaunchKernelGGL(h_kernel, dim3(NB), dim3(256), 0, stream,
                       adj, w1, b1, H);
    hipLaunchKernelGGL(fused_kernel, dim3(BT, 2), dim3(256), 0, stream,
                       x, w2, b2, node_w, node_b, H, out);
}